// Round 1
// baseline (11017.456 us; speedup 1.0000x reference)
//
#include <hip/hip_runtime.h>

#define DH 256
#define DS 552
#define DS_PAD 576
#define NG 1024
#define NBATCH 64
#define LTOK 128
#define STEPS_DEC 1000
#define ST_TRUE 800
#define TOTAL_STEPS (LTOK + STEPS_DEC)
#define NBLK_REC 64

typedef __attribute__((ext_vector_type(8))) short bf16x8;
typedef __attribute__((ext_vector_type(4))) float f32x4;

// ---------- workspace layout (bytes) ----------
#define OFF_CNT      0              // unsigned
#define OFF_GEN      128            // unsigned
#define OFF_HPL      512            // h planes: [par][hi/lo][64][256] bf16 = 131072 B
#define OFF_WHE_HI   131584         // enc Whh hi [1024][256] bf16
#define OFF_WHE_LO   655872
#define OFF_WHD_HI   1180160        // dec Whh hi
#define OFF_WHD_LO   1704448
#define OFF_WC_HI    2228736        // Wcomb hi [1024][576] bf16
#define OFF_WC_LO    3408384
#define OFF_W1_HI    4588032        // post_W1 [256][256]
#define OFF_W1_LO    4719104
#define OFF_W2_HI    4850176        // post_W2 padded [576][256]
#define OFF_W2_LO    5145088
#define OFF_SW1_HI   5440000        // stop_W1 [256][256]
#define OFF_SW1_LO   5571072
#define OFF_EMB2     5702144        // [148][1024] f32 (enc x-gates incl biases)
#define OFF_BCOMB    6308352        // [1024] f32
#define OFF_WCF      6312448        // Wcomb f32 scratch [1024][552]
#define OFF_HBF      8573440        // H archive [64000][256] bf16
#define OFF_GX       41341440       // gx [1000][64][1024] fp16
#define OFF_HID      OFF_GX         // overlay: hid [64000][256] bf16 (gx dead by then)
#define OFF_SH       74109440       // sh  [64000][256] bf16
#define WS_NEED      172413440ULL

__device__ __forceinline__ unsigned short f2bf_rn(float x) {
  unsigned u = __builtin_bit_cast(unsigned, x);
  u += 0x7fffu + ((u >> 16) & 1u);
  return (unsigned short)(u >> 16);
}
__device__ __forceinline__ float bf2f(unsigned short h) {
  unsigned u = ((unsigned)h) << 16;
  return __builtin_bit_cast(float, u);
}
__device__ __forceinline__ f32x4 mfma16(bf16x8 a, bf16x8 b, f32x4 c) {
  return __builtin_amdgcn_mfma_f32_16x16x32_bf16(a, b, c, 0, 0, 0);
}

// ---------- prep: Wcomb = dec_Wih @ pre_W, bcomb = dec_Wih@pre_b + bih + bhh ----------
__global__ __launch_bounds__(256) void prep_wcomb_kernel(
    const float* __restrict__ Wih, const float* __restrict__ preW,
    const float* __restrict__ pre_b, const float* __restrict__ bih,
    const float* __restrict__ bhh, float* __restrict__ WcombF,
    float* __restrict__ bcomb) {
  __shared__ float row[DH];
  __shared__ float red[256];
  int g = blockIdx.x, tid = threadIdx.x;
  row[tid] = Wih[g * DH + tid];
  __syncthreads();
  float a0 = 0.f, a1 = 0.f, a2 = 0.f;
  for (int j = 0; j < DH; ++j) {
    float wv = row[j];
    const float* pr = preW + j * DS;
    a0 += wv * pr[tid];
    a1 += wv * pr[tid + 256];
    if (tid < DS - 512) a2 += wv * pr[tid + 512];
  }
  WcombF[g * DS + tid] = a0;
  WcombF[g * DS + tid + 256] = a1;
  if (tid < DS - 512) WcombF[g * DS + tid + 512] = a2;
  red[tid] = row[tid] * pre_b[tid];
  __syncthreads();
  for (int s = 128; s > 0; s >>= 1) {
    if (tid < s) red[tid] += red[tid + s];
    __syncthreads();
  }
  if (tid == 0) bcomb[g] = red[0] + bih[g] + bhh[g];
}

// ---------- prep: emb2[v][g] = emb[v] . enc_Wih[g] + bih[g] + bhh[g] ----------
__global__ __launch_bounds__(256) void prep_emb2_kernel(
    const float* __restrict__ emb, const float* __restrict__ Wih,
    const float* __restrict__ bih, const float* __restrict__ bhh,
    float* __restrict__ emb2) {
  __shared__ float erow[DH];
  int v = blockIdx.x, tid = threadIdx.x;
  erow[tid] = emb[v * DH + tid];
  __syncthreads();
  for (int c = 0; c < 4; ++c) {
    int g = c * 256 + tid;
    const float* wr = Wih + g * DH;
    float acc = 0.f;
    for (int j = 0; j < DH; ++j) acc += erow[j] * wr[j];
    emb2[v * NG + g] = acc + bih[g] + bhh[g];
  }
}

// ---------- split fp32 -> bf16 hi/lo planes ----------
__global__ void split_bf16_kernel(const float* __restrict__ src,
                                  unsigned short* __restrict__ hi,
                                  unsigned short* __restrict__ lo,
                                  int rows, int cols, int ldo) {
  int idx = blockIdx.x * 256 + threadIdx.x;
  if (idx >= rows * cols) return;
  int r = idx / cols, c = idx - r * cols;
  float x = src[idx];
  unsigned short h = f2bf_rn(x);
  hi[r * ldo + c] = h;
  lo[r * ldo + c] = f2bf_rn(x - bf2f(h));
}

// ---------- gx = S_in @ Wcomb.T, fp16 out, split-bf16 3-term MFMA ----------
__global__ __launch_bounds__(256) void gx_gemm_kernel(
    const float* __restrict__ Strue, const unsigned short* __restrict__ Whi,
    const unsigned short* __restrict__ Wlo, _Float16* __restrict__ gx) {
  int t = blockIdx.y + 1;           // 1..799
  int n0 = blockIdx.x * 64;
  int tid = threadIdx.x;
  int w = tid >> 6, lane = tid & 63, quad = lane >> 4, lrow = lane & 15;
  int mrow = t * 64 + w * 16 + lrow;
  f32x4 acc[4];
#pragma unroll
  for (int j = 0; j < 4; ++j) acc[j] = (f32x4){0.f, 0.f, 0.f, 0.f};
  for (int ks = 0; ks < 18; ++ks) {
    int kb = ks * 32 + quad * 8;
    bf16x8 ah, al;
    if (kb < DS) {
      const float* ap = Strue + (size_t)mrow * DS + kb;
      float4 x0 = *(const float4*)ap;
      float4 x1 = *(const float4*)(ap + 4);
      float xs[8] = {x0.x, x0.y, x0.z, x0.w, x1.x, x1.y, x1.z, x1.w};
#pragma unroll
      for (int j = 0; j < 8; ++j) {
        unsigned u = __builtin_bit_cast(unsigned, xs[j]);
        unsigned short h = (unsigned short)(u >> 16);  // RTZ hi
        ah[j] = (short)h;
        al[j] = (short)f2bf_rn(xs[j] - bf2f(h));
      }
    } else {
#pragma unroll
      for (int j = 0; j < 8; ++j) { ah[j] = 0; al[j] = 0; }
    }
#pragma unroll
    for (int j = 0; j < 4; ++j) {
      int n = n0 + j * 16 + lrow;
      bf16x8 bh = *(const bf16x8*)(Whi + (size_t)n * DS_PAD + kb);
      bf16x8 bl = *(const bf16x8*)(Wlo + (size_t)n * DS_PAD + kb);
      acc[j] = mfma16(ah, bh, acc[j]);
      acc[j] = mfma16(al, bh, acc[j]);
      acc[j] = mfma16(ah, bl, acc[j]);
    }
  }
#pragma unroll
  for (int j = 0; j < 4; ++j) {
    int n = n0 + j * 16 + lrow;
#pragma unroll
    for (int r = 0; r < 4; ++r) {
      int m = t * 64 + w * 16 + quad * 4 + r;
      gx[(size_t)m * NG + n] = (_Float16)acc[j][r];
    }
  }
}

// ---------- grid barrier (64 co-resident blocks) ----------
__device__ __forceinline__ void grid_barrier(unsigned* cnt, unsigned* gen,
                                             unsigned g) {
  __syncthreads();
  if (threadIdx.x == 0) {
    unsigned prev = __hip_atomic_fetch_add(cnt, 1u, __ATOMIC_ACQ_REL,
                                           __HIP_MEMORY_SCOPE_AGENT);
    if (prev == g * NBLK_REC - 1u) {
      __hip_atomic_store(gen, g, __ATOMIC_RELEASE, __HIP_MEMORY_SCOPE_AGENT);
    } else {
      while (__hip_atomic_load(gen, __ATOMIC_RELAXED,
                               __HIP_MEMORY_SCOPE_AGENT) < g) {
        __builtin_amdgcn_s_sleep(1);
      }
      __threadfence();
    }
  }
  __syncthreads();
}

// ---------- persistent recurrence: encoder (128) + decoder (1000) ----------
__global__ __launch_bounds__(256, 1) void recurrence_kernel(
    const unsigned short* __restrict__ whe_hi, const unsigned short* __restrict__ whe_lo,
    const unsigned short* __restrict__ whd_hi, const unsigned short* __restrict__ whd_lo,
    const float* __restrict__ emb2, const int* __restrict__ token_pad,
    const int* __restrict__ token_len, const _Float16* __restrict__ gx,
    const float* __restrict__ bcomb, unsigned short* __restrict__ hplanes,
    unsigned short* __restrict__ Hbf, unsigned* cnt, unsigned* gen) {
  __shared__ __align__(16) float G[64 * 20];
  int tid = threadIdx.x;
  int rb = blockIdx.x;
  int w = tid >> 6, lane = tid & 63, quad = lane >> 4, lrow = lane & 15;
  // B fragment row (N order: n = unit_local*4 + gate_type)
  int tt_b = lrow & 3, uu_b = lrow >> 2;
  int grow = 256 * tt_b + rb * 4 + uu_b;
  // nonlinearity role
  int b = tid & 63, u = tid >> 6;
  int ug = rb * 4 + u;
  float c = 0.f, h_own = 0.f;
  int len = token_len[b];
  float bc[4];
#pragma unroll
  for (int t = 0; t < 4; ++t) bc[t] = bcomb[256 * t + ug];
  bf16x8 Bh[8], Bl[8];
#pragma unroll
  for (int ks = 0; ks < 8; ++ks) {
    Bh[ks] = *(const bf16x8*)(whe_hi + (size_t)grow * DH + ks * 32 + quad * 8);
    Bl[ks] = *(const bf16x8*)(whe_lo + (size_t)grow * DH + ks * 32 + quad * 8);
  }
  for (int S = 0; S < TOTAL_STEPS; ++S) {
    if (S == LTOK) {
      // switch to decoder weights; decoder init: (h,c) = (enc_out, enc_out)
#pragma unroll
      for (int ks = 0; ks < 8; ++ks) {
        Bh[ks] = *(const bf16x8*)(whd_hi + (size_t)grow * DH + ks * 32 + quad * 8);
        Bl[ks] = *(const bf16x8*)(whd_lo + (size_t)grow * DH + ks * 32 + quad * 8);
      }
      c = h_own;
    }
    grid_barrier(cnt, gen, (unsigned)(S + 1));
    // issue input-gate loads early (overlap with A-frag loads + MFMA)
    float x0 = 0.f, x1 = 0.f, x2 = 0.f, x3 = 0.f;
    if (S < LTOK) {
      int tok = token_pad[S * 64 + b];
      const float* e = emb2 + (size_t)tok * NG + ug;
      x0 = e[0]; x1 = e[256]; x2 = e[512]; x3 = e[768];
    } else {
      int d = S - LTOK;
      if (d >= 1 && d < ST_TRUE) {
        const _Float16* gp = gx + (size_t)d * (64 * NG) + (size_t)b * NG + ug;
        x0 = (float)gp[0]; x1 = (float)gp[256];
        x2 = (float)gp[512]; x3 = (float)gp[768];
      }
    }
    int par = S & 1;
    const unsigned short* hhi = hplanes + par * (2 * NBATCH * DH);
    const unsigned short* hlo = hhi + NBATCH * DH;
    int arow = w * 16 + lrow;
    bf16x8 Ah[8], Al[8];
#pragma unroll
    for (int ks = 0; ks < 8; ++ks) {
      Ah[ks] = *(const bf16x8*)(hhi + arow * DH + ks * 32 + quad * 8);
      Al[ks] = *(const bf16x8*)(hlo + arow * DH + ks * 32 + quad * 8);
    }
    f32x4 a1 = (f32x4){0.f, 0.f, 0.f, 0.f};
    f32x4 a2 = (f32x4){0.f, 0.f, 0.f, 0.f};
    f32x4 a3 = (f32x4){0.f, 0.f, 0.f, 0.f};
#pragma unroll
    for (int ks = 0; ks < 8; ++ks) {
      a1 = mfma16(Ah[ks], Bh[ks], a1);
      a2 = mfma16(Al[ks], Bh[ks], a2);
      a3 = mfma16(Ah[ks], Bl[ks], a3);
    }
    f32x4 s = a1 + a2 + a3;
#pragma unroll
    for (int r = 0; r < 4; ++r) {
      int bb = w * 16 + quad * 4 + r;
      G[bb * 20 + lrow] = s[r];
    }
    __syncthreads();
    f32x4 gv = *(const f32x4*)&G[b * 20 + u * 4];
    float gI, gF, gG, gO;
    if (S < LTOK) {
      gI = gv[0] + x0; gF = gv[1] + x1; gG = gv[2] + x2; gO = gv[3] + x3;
    } else {
      gI = gv[0] + bc[0] + x0; gF = gv[1] + bc[1] + x1;
      gG = gv[2] + bc[2] + x2; gO = gv[3] + bc[3] + x3;
    }
    float si = 1.f / (1.f + expf(-gI));
    float sf = 1.f / (1.f + expf(-gF));
    float so = 1.f / (1.f + expf(-gO));
    float c2 = sf * c + si * tanhf(gG);
    float h2 = so * tanhf(c2);
    if (S < LTOK && S >= len) { c2 = c; h2 = h_own; }  // encoder mask
    c = c2; h_own = h2;
    unsigned short hh = f2bf_rn(h2);
    unsigned short hl = f2bf_rn(h2 - bf2f(hh));
    unsigned short* ohi = hplanes + (par ^ 1) * (2 * NBATCH * DH);
    ohi[b * DH + ug] = hh;
    ohi[NBATCH * DH + b * DH + ug] = hl;
    if (S >= LTOK) {
      int d = S - LTOK;
      Hbf[((size_t)d * 64 + b) * DH + ug] = hh;
    }
  }
}

// ---------- post GEMMs: C = act(A @ B.T + bias) ----------
// mode 0/1: relu -> bf16 out [M][256]; mode 2: fp32 out [M][552]
__global__ __launch_bounds__(256) void hgemm_kernel(
    const unsigned short* __restrict__ A, const unsigned short* __restrict__ Bhi,
    const unsigned short* __restrict__ Blo, const float* __restrict__ bias,
    unsigned short* __restrict__ outBf, float* __restrict__ outF, int Ncols,
    int mode) {
  int m0 = blockIdx.y * 64;
  int n0 = blockIdx.x * 64;
  int tid = threadIdx.x;
  int w = tid >> 6, lane = tid & 63, quad = lane >> 4, lrow = lane & 15;
  int ma = m0 + w * 16 + lrow;
  f32x4 acc[4];
#pragma unroll
  for (int j = 0; j < 4; ++j) acc[j] = (f32x4){0.f, 0.f, 0.f, 0.f};
  for (int ks = 0; ks < 8; ++ks) {
    int kb = ks * 32 + quad * 8;
    bf16x8 af = *(const bf16x8*)(A + (size_t)ma * DH + kb);
#pragma unroll
    for (int j = 0; j < 4; ++j) {
      int n = n0 + j * 16 + lrow;
      bf16x8 bh = *(const bf16x8*)(Bhi + (size_t)n * DH + kb);
      bf16x8 bl = *(const bf16x8*)(Blo + (size_t)n * DH + kb);
      acc[j] = mfma16(af, bh, acc[j]);
      acc[j] = mfma16(af, bl, acc[j]);
    }
  }
#pragma unroll
  for (int j = 0; j < 4; ++j) {
    int n = n0 + j * 16 + lrow;
    float bv = (n < Ncols) ? bias[n] : 0.f;
#pragma unroll
    for (int r = 0; r < 4; ++r) {
      int m = m0 + w * 16 + quad * 4 + r;
      float v = acc[j][r] + bv;
      if (mode < 2) {
        v = fmaxf(v, 0.f);
        outBf[(size_t)m * DH + n] = f2bf_rn(v);
      } else if (n < Ncols) {
        outF[(size_t)m * DS + n] = v;
      }
    }
  }
}

// ---------- stop logits: out[m] = sh[m] . w2 + b2 ----------
__global__ __launch_bounds__(256) void stop_kernel(
    const unsigned short* __restrict__ sh, const float* __restrict__ w2,
    const float* __restrict__ b2, float* __restrict__ out) {
  int m = blockIdx.x * 256 + threadIdx.x;
  const unsigned short* row = sh + (size_t)m * DH;
  float acc = 0.f;
  for (int k = 0; k < DH; k += 8) {
    bf16x8 v = *(const bf16x8*)(row + k);
#pragma unroll
    for (int j = 0; j < 8; ++j)
      acc += bf2f((unsigned short)v[j]) * w2[k + j];
  }
  out[m] = acc + b2[0];
}

extern "C" void kernel_launch(void* const* d_in, const int* in_sizes, int n_in,
                              void* d_out, int out_size, void* d_ws,
                              size_t ws_size, hipStream_t stream) {
  const int* token_pad = (const int*)d_in[0];
  const int* token_len = (const int*)d_in[1];
  const float* S_true = (const float*)d_in[2];
  const float* emb = (const float*)d_in[3];
  const float* enc_Wih = (const float*)d_in[4];
  const float* enc_Whh = (const float*)d_in[5];
  const float* enc_bih = (const float*)d_in[6];
  const float* enc_bhh = (const float*)d_in[7];
  const float* dec_Wih = (const float*)d_in[8];
  const float* dec_Whh = (const float*)d_in[9];
  const float* dec_bih = (const float*)d_in[10];
  const float* dec_bhh = (const float*)d_in[11];
  const float* pre_W = (const float*)d_in[12];
  const float* pre_b = (const float*)d_in[13];
  const float* post_W1 = (const float*)d_in[14];
  const float* post_b1 = (const float*)d_in[15];
  const float* post_W2 = (const float*)d_in[16];
  const float* post_b2 = (const float*)d_in[17];
  const float* stop_W1 = (const float*)d_in[18];
  const float* stop_b1 = (const float*)d_in[19];
  const float* stop_W2 = (const float*)d_in[20];
  const float* stop_b2 = (const float*)d_in[21];

  if (ws_size < WS_NEED) return;  // fail loudly rather than corrupt
  char* ws = (char*)d_ws;
  unsigned* cnt = (unsigned*)(ws + OFF_CNT);
  unsigned* gen = (unsigned*)(ws + OFF_GEN);
  unsigned short* hplanes = (unsigned short*)(ws + OFF_HPL);
  unsigned short* whe_hi = (unsigned short*)(ws + OFF_WHE_HI);
  unsigned short* whe_lo = (unsigned short*)(ws + OFF_WHE_LO);
  unsigned short* whd_hi = (unsigned short*)(ws + OFF_WHD_HI);
  unsigned short* whd_lo = (unsigned short*)(ws + OFF_WHD_LO);
  unsigned short* wc_hi = (unsigned short*)(ws + OFF_WC_HI);
  unsigned short* wc_lo = (unsigned short*)(ws + OFF_WC_LO);
  unsigned short* w1_hi = (unsigned short*)(ws + OFF_W1_HI);
  unsigned short* w1_lo = (unsigned short*)(ws + OFF_W1_LO);
  unsigned short* w2_hi = (unsigned short*)(ws + OFF_W2_HI);
  unsigned short* w2_lo = (unsigned short*)(ws + OFF_W2_LO);
  unsigned short* sw1_hi = (unsigned short*)(ws + OFF_SW1_HI);
  unsigned short* sw1_lo = (unsigned short*)(ws + OFF_SW1_LO);
  float* emb2 = (float*)(ws + OFF_EMB2);
  float* bcomb = (float*)(ws + OFF_BCOMB);
  float* WcombF = (float*)(ws + OFF_WCF);
  unsigned short* Hbf = (unsigned short*)(ws + OFF_HBF);
  _Float16* gx = (_Float16*)(ws + OFF_GX);
  unsigned short* hid = (unsigned short*)(ws + OFF_HID);
  unsigned short* shb = (unsigned short*)(ws + OFF_SH);
  float* outS = (float*)d_out;
  float* outStop = outS + (size_t)STEPS_DEC * 64 * DS;

  // zero: barrier + h planes; padded weight planes
  hipMemsetAsync(ws + OFF_CNT, 0, 131584, stream);
  hipMemsetAsync(ws + OFF_WC_HI, 0, 2359296, stream);
  hipMemsetAsync(ws + OFF_W2_HI, 0, 589824, stream);

  prep_wcomb_kernel<<<1024, 256, 0, stream>>>(dec_Wih, pre_W, pre_b, dec_bih,
                                              dec_bhh, WcombF, bcomb);
  prep_emb2_kernel<<<148, 256, 0, stream>>>(emb, enc_Wih, enc_bih, enc_bhh,
                                            emb2);
  split_bf16_kernel<<<(1024 * 552 + 255) / 256, 256, 0, stream>>>(
      WcombF, wc_hi, wc_lo, 1024, 552, 576);
  split_bf16_kernel<<<(1024 * 256 + 255) / 256, 256, 0, stream>>>(
      dec_Whh, whd_hi, whd_lo, 1024, 256, 256);
  split_bf16_kernel<<<(1024 * 256 + 255) / 256, 256, 0, stream>>>(
      enc_Whh, whe_hi, whe_lo, 1024, 256, 256);
  split_bf16_kernel<<<(256 * 256 + 255) / 256, 256, 0, stream>>>(
      post_W1, w1_hi, w1_lo, 256, 256, 256);
  split_bf16_kernel<<<(552 * 256 + 255) / 256, 256, 0, stream>>>(
      post_W2, w2_hi, w2_lo, 552, 256, 256);
  split_bf16_kernel<<<(256 * 256 + 255) / 256, 256, 0, stream>>>(
      stop_W1, sw1_hi, sw1_lo, 256, 256, 256);

  gx_gemm_kernel<<<dim3(16, 799), 256, 0, stream>>>(S_true, wc_hi, wc_lo, gx);

  recurrence_kernel<<<NBLK_REC, 256, 0, stream>>>(
      whe_hi, whe_lo, whd_hi, whd_lo, emb2, token_pad, token_len, gx, bcomb,
      hplanes, Hbf, cnt, gen);

  hgemm_kernel<<<dim3(4, 1000), 256, 0, stream>>>(Hbf, w1_hi, w1_lo, post_b1,
                                                  hid, nullptr, 256, 0);
  hgemm_kernel<<<dim3(4, 1000), 256, 0, stream>>>(Hbf, sw1_hi, sw1_lo, stop_b1,
                                                  shb, nullptr, 256, 1);
  hgemm_kernel<<<dim3(9, 1000), 256, 0, stream>>>(hid, w2_hi, w2_lo, post_b2,
                                                  nullptr, outS, 552, 2);
  stop_kernel<<<250, 256, 0, stream>>>(shb, stop_W2, stop_b2, outStop);
}

// Round 2
// 9589.297 us; speedup vs baseline: 1.1489x; 1.1489x over previous
//
#include <hip/hip_runtime.h>

#define DH 256
#define DS 552
#define DS_PAD 576
#define NG 1024
#define LTOK 128
#define STEPS_DEC 1000
#define ST_TRUE 800
#define TOTAL_STEPS (LTOK + STEPS_DEC)
#define NREC 16
#define GRID_BLKS 128
#define NHELP (GRID_BLKS - NREC)
#define LDG 68    // G LDS stride (floats)
#define LDH 264   // hid/sh LDS stride (shorts)

typedef __attribute__((ext_vector_type(8))) short bf16x8;
typedef __attribute__((ext_vector_type(4))) float f32x4;

// ---------- workspace layout (bytes) ----------
#define OFF_FLAGS    0            // 16 flags x 256B
#define OFF_GXD      4096         // 800 x u32 (+pad)
#define OFF_HPL      8192         // h planes [2 par][2 pl][64][256] bf16 = 131072
#define OFF_WHE_HI   139264
#define OFF_WHE_LO   663552
#define OFF_WHD_HI   1187840
#define OFF_WHD_LO   1712128
#define OFF_WC_HI    2236416      // [1024][576]
#define OFF_WC_LO    3416064
#define OFF_W1_HI    4595712
#define OFF_W1_LO    4726784
#define OFF_W2_HI    4857856      // [576][256] (rows 552.. zero)
#define OFF_W2_LO    5152768
#define OFF_SW1_HI   5447680
#define OFF_SW1_LO   5578752
#define OFF_EMB2     5709824      // [148][1024] f32
#define OFF_BCOMB    6316032
#define OFF_WCF      6320128      // [1024][552] f32 scratch
#define OFF_HBF      8581120      // [1000][64][256] bf16
#define OFF_GX       41349120     // [800][64][1024] fp16
#define WS_NEED      146206720ULL

__device__ __forceinline__ unsigned short f2bf_rn(float x) {
  unsigned u = __builtin_bit_cast(unsigned, x);
  u += 0x7fffu + ((u >> 16) & 1u);
  return (unsigned short)(u >> 16);
}
__device__ __forceinline__ float bf2f(unsigned short h) {
  unsigned u = ((unsigned)h) << 16;
  return __builtin_bit_cast(float, u);
}
__device__ __forceinline__ f32x4 mfma16(bf16x8 a, bf16x8 b, f32x4 c) {
  return __builtin_amdgcn_mfma_f32_16x16x32_bf16(a, b, c, 0, 0, 0);
}

// ---------- prep kernels (unchanged from round 1) ----------
__global__ __launch_bounds__(256) void prep_wcomb_kernel(
    const float* __restrict__ Wih, const float* __restrict__ preW,
    const float* __restrict__ pre_b, const float* __restrict__ bih,
    const float* __restrict__ bhh, float* __restrict__ WcombF,
    float* __restrict__ bcomb) {
  __shared__ float row[DH];
  __shared__ float red[256];
  int g = blockIdx.x, tid = threadIdx.x;
  row[tid] = Wih[g * DH + tid];
  __syncthreads();
  float a0 = 0.f, a1 = 0.f, a2 = 0.f;
  for (int j = 0; j < DH; ++j) {
    float wv = row[j];
    const float* pr = preW + j * DS;
    a0 += wv * pr[tid];
    a1 += wv * pr[tid + 256];
    if (tid < DS - 512) a2 += wv * pr[tid + 512];
  }
  WcombF[g * DS + tid] = a0;
  WcombF[g * DS + tid + 256] = a1;
  if (tid < DS - 512) WcombF[g * DS + tid + 512] = a2;
  red[tid] = row[tid] * pre_b[tid];
  __syncthreads();
  for (int s = 128; s > 0; s >>= 1) {
    if (tid < s) red[tid] += red[tid + s];
    __syncthreads();
  }
  if (tid == 0) bcomb[g] = red[0] + bih[g] + bhh[g];
}

__global__ __launch_bounds__(256) void prep_emb2_kernel(
    const float* __restrict__ emb, const float* __restrict__ Wih,
    const float* __restrict__ bih, const float* __restrict__ bhh,
    float* __restrict__ emb2) {
  __shared__ float erow[DH];
  int v = blockIdx.x, tid = threadIdx.x;
  erow[tid] = emb[v * DH + tid];
  __syncthreads();
  for (int c = 0; c < 4; ++c) {
    int g = c * 256 + tid;
    const float* wr = Wih + g * DH;
    float acc = 0.f;
    for (int j = 0; j < DH; ++j) acc += erow[j] * wr[j];
    emb2[v * NG + g] = acc + bih[g] + bhh[g];
  }
}

__global__ void split_bf16_kernel(const float* __restrict__ src,
                                  unsigned short* __restrict__ hi,
                                  unsigned short* __restrict__ lo,
                                  int rows, int cols, int ldo) {
  int idx = blockIdx.x * 256 + threadIdx.x;
  if (idx >= rows * cols) return;
  int r = idx / cols, c = idx - r * cols;
  float x = src[idx];
  unsigned short h = f2bf_rn(x);
  hi[r * ldo + c] = h;
  lo[r * ldo + c] = f2bf_rn(x - bf2f(h));
}

// ---------- shared memory union ----------
union SharedU {
  struct { float G[64 * LDG]; } rec;
  struct {
    unsigned short hid[64 * LDH];
    unsigned short sh[64 * LDH];
    float red[256];
  } post;
};

// ---------- mega kernel: 16 recurrence blocks + 112 helper blocks ----------
__global__ __launch_bounds__(256, 1) void mega_kernel(
    const unsigned short* __restrict__ whe_hi, const unsigned short* __restrict__ whe_lo,
    const unsigned short* __restrict__ whd_hi, const unsigned short* __restrict__ whd_lo,
    const unsigned short* __restrict__ wc_hi, const unsigned short* __restrict__ wc_lo,
    const unsigned short* __restrict__ w1_hi, const unsigned short* __restrict__ w1_lo,
    const unsigned short* __restrict__ w2_hi, const unsigned short* __restrict__ w2_lo,
    const unsigned short* __restrict__ sw1_hi, const unsigned short* __restrict__ sw1_lo,
    const float* __restrict__ emb2, const float* __restrict__ bcomb,
    const int* __restrict__ token_pad, const int* __restrict__ token_len,
    const float* __restrict__ Strue,
    const float* __restrict__ post_b1, const float* __restrict__ post_b2,
    const float* __restrict__ stop_b1, const float* __restrict__ stop_w2,
    const float* __restrict__ stop_b2,
    unsigned short* __restrict__ hpl, unsigned short* __restrict__ Hbf,
    _Float16* __restrict__ gx, unsigned* flags, unsigned* gxdone,
    float* __restrict__ outS, float* __restrict__ outStop) {
  __shared__ SharedU smem;
  int tid = threadIdx.x;
  int w = tid >> 6, lane = tid & 63, quad = lane >> 4, lrow = lane & 15;

  if (blockIdx.x < NREC) {
    // ================= persistent recurrence =================
    int rb = blockIdx.x;
    int b = lane;                 // nonlin batch role
    int u0 = w * 4;               // 4 local units per thread (contiguous)
    int gub = 16 * rb + u0;       // global unit base
    int len = token_len[b];
    float bc[16];
#pragma unroll
    for (int i = 0; i < 4; ++i)
#pragma unroll
      for (int g = 0; g < 4; ++g) bc[i * 4 + g] = bcomb[g * 256 + gub + i];
    // B-frags (weights) fully in VGPRs: n-tile j, lane lrow -> nloc = 16j+lrow
    int grow0 = (lrow & 3) * 256 + 16 * rb + (lrow >> 2);
    bf16x8 Bh[4][8], Bl[4][8];
#pragma unroll
    for (int j = 0; j < 4; ++j)
#pragma unroll
      for (int ks = 0; ks < 8; ++ks) {
        size_t off = (size_t)(grow0 + 4 * j) * DH + ks * 32 + quad * 8;
        Bh[j][ks] = *(const bf16x8*)(whe_hi + off);
        Bl[j][ks] = *(const bf16x8*)(whe_lo + off);
      }
    float c[4] = {0.f, 0.f, 0.f, 0.f}, h[4] = {0.f, 0.f, 0.f, 0.f};
    float xc[16], xn[16];
    {  // x for S=0 (encoder)
      int tok = token_pad[b];
#pragma unroll
      for (int i = 0; i < 4; ++i)
#pragma unroll
        for (int g = 0; g < 4; ++g)
          xc[i * 4 + g] = emb2[(size_t)tok * NG + g * 256 + gub + i];
    }
    int gxwm = 0;
    float* G = smem.rec.G;
    for (int S = 0; S < TOTAL_STEPS; ++S) {
      if (S == LTOK) {  // swap to decoder weights; (h,c) = (enc_out, enc_out)
#pragma unroll
        for (int j = 0; j < 4; ++j)
#pragma unroll
          for (int ks = 0; ks < 8; ++ks) {
            size_t off = (size_t)(grow0 + 4 * j) * DH + ks * 32 + quad * 8;
            Bh[j][ks] = *(const bf16x8*)(whd_hi + off);
            Bl[j][ks] = *(const bf16x8*)(whd_lo + off);
          }
#pragma unroll
        for (int i = 0; i < 4; ++i) c[i] = h[i];
      }
      int dn = S + 1 - LTOK;  // decoder index of NEXT step's x
      // 1. gx readiness (uniform; no-op once helpers are ahead)
      if (dn >= 1 && dn < ST_TRUE) {
        while (gxwm < dn) {
          if (__hip_atomic_load(&gxdone[gxwm + 1], __ATOMIC_RELAXED,
                                __HIP_MEMORY_SCOPE_AGENT) >= 16u)
            ++gxwm;
          else
            __builtin_amdgcn_s_sleep(1);
        }
      }
      // 2. peer h flags >= S
      {
        const unsigned* fp = &flags[(lane & 15) * 64];
        unsigned tgt = (unsigned)S;
        for (;;) {
          unsigned f =
              __hip_atomic_load(fp, __ATOMIC_RELAXED, __HIP_MEMORY_SCOPE_AGENT);
          if (__all(f >= tgt)) break;
          __builtin_amdgcn_s_sleep(1);
        }
      }
      __builtin_amdgcn_fence(__ATOMIC_ACQUIRE, "agent");
      // 3. prefetch x for step S+1 (consumed next iteration)
      if (S + 1 < LTOK) {
        int tok = token_pad[(S + 1) * 64 + b];
#pragma unroll
        for (int i = 0; i < 4; ++i)
#pragma unroll
          for (int g = 0; g < 4; ++g)
            xn[i * 4 + g] = emb2[(size_t)tok * NG + g * 256 + gub + i];
      } else if (dn >= 1 && dn < ST_TRUE) {
        const _Float16* gp = gx + ((size_t)dn * 64 + b) * NG;
#pragma unroll
        for (int i = 0; i < 4; ++i)
#pragma unroll
          for (int g = 0; g < 4; ++g)
            xn[i * 4 + g] = (float)gp[g * 256 + gub + i];
      } else {
#pragma unroll
        for (int k = 0; k < 16; ++k) xn[k] = 0.f;
      }
      // 4. A-frags (h hi/lo) from global
      const unsigned short* hb = hpl + ((S & 1) << 15);
      int arow = w * 16 + lrow;
      bf16x8 Ah[8], Al[8];
#pragma unroll
      for (int ks = 0; ks < 8; ++ks) {
        Ah[ks] = *(const bf16x8*)(hb + arow * 256 + ks * 32 + quad * 8);
        Al[ks] = *(const bf16x8*)(hb + 16384 + arow * 256 + ks * 32 + quad * 8);
      }
      // 5. MFMA: G-slice 64x64, 3-term split
      f32x4 acc[4];
#pragma unroll
      for (int j = 0; j < 4; ++j) acc[j] = (f32x4){0.f, 0.f, 0.f, 0.f};
#pragma unroll
      for (int ks = 0; ks < 8; ++ks)
#pragma unroll
        for (int j = 0; j < 4; ++j) {
          acc[j] = mfma16(Ah[ks], Bh[j][ks], acc[j]);
          acc[j] = mfma16(Al[ks], Bh[j][ks], acc[j]);
          acc[j] = mfma16(Ah[ks], Bl[j][ks], acc[j]);
        }
      // 6. G -> LDS  (layout [nloc][b])
#pragma unroll
      for (int j = 0; j < 4; ++j)
        *(f32x4*)&G[(16 * j + lrow) * LDG + 16 * w + quad * 4] = acc[j];
      __syncthreads();
      // 7. nonlinearity: 4 cells (b, gub..gub+3)
      unsigned hv0, hv1, lv0, lv1;
      {
        unsigned short hhs[4], hls[4];
#pragma unroll
        for (int i = 0; i < 4; ++i) {
          float gI = G[(4 * (u0 + i) + 0) * LDG + b];
          float gF = G[(4 * (u0 + i) + 1) * LDG + b];
          float gG = G[(4 * (u0 + i) + 2) * LDG + b];
          float gO = G[(4 * (u0 + i) + 3) * LDG + b];
          if (S < LTOK) {
            gI += xc[i * 4 + 0]; gF += xc[i * 4 + 1];
            gG += xc[i * 4 + 2]; gO += xc[i * 4 + 3];
          } else {
            gI += bc[i * 4 + 0] + xc[i * 4 + 0];
            gF += bc[i * 4 + 1] + xc[i * 4 + 1];
            gG += bc[i * 4 + 2] + xc[i * 4 + 2];
            gO += bc[i * 4 + 3] + xc[i * 4 + 3];
          }
          float si = 1.f / (1.f + expf(-gI));
          float sf = 1.f / (1.f + expf(-gF));
          float so = 1.f / (1.f + expf(-gO));
          float c2 = sf * c[i] + si * tanhf(gG);
          float h2 = so * tanhf(c2);
          if (S < LTOK && S >= len) { c2 = c[i]; h2 = h[i]; }
          c[i] = c2; h[i] = h2;
          unsigned short hh = f2bf_rn(h2);
          hhs[i] = hh;
          hls[i] = f2bf_rn(h2 - bf2f(hh));
        }
        hv0 = (unsigned)hhs[0] | ((unsigned)hhs[1] << 16);
        hv1 = (unsigned)hhs[2] | ((unsigned)hhs[3] << 16);
        lv0 = (unsigned)hls[0] | ((unsigned)hls[1] << 16);
        lv1 = (unsigned)hls[2] | ((unsigned)hls[3] << 16);
      }
      // 8. publish h (packed 8B chunks) + Hbf
      unsigned short* ob = hpl + (((S & 1) ^ 1) << 15);
      *(uint2*)&ob[b * 256 + gub] = make_uint2(hv0, hv1);
      *(uint2*)&ob[16384 + b * 256 + gub] = make_uint2(lv0, lv1);
      if (S >= LTOK) {
        int d = S - LTOK;
        *(uint2*)&Hbf[((size_t)d * 64 + b) * 256 + gub] = make_uint2(hv0, hv1);
      }
#pragma unroll
      for (int k = 0; k < 16; ++k) xc[k] = xn[k];
      __syncthreads();  // drains each wave's vmcnt; also protects G reuse
      if (tid == 0) {
        __builtin_amdgcn_fence(__ATOMIC_RELEASE, "agent");
        __hip_atomic_store(&flags[rb * 64], (unsigned)(S + 1), __ATOMIC_RELAXED,
                           __HIP_MEMORY_SCOPE_AGENT);
      }
    }
  } else {
    // ================= helpers =================
    int hid0 = blockIdx.x - NREC;
    // ---- phase 1: gx tiles (t ascending) ----
    for (int item = hid0; item < 799 * 16; item += NHELP) {
      int t = 1 + (item >> 4);
      int n0 = (item & 15) << 6;
      f32x4 acc[4];
#pragma unroll
      for (int j = 0; j < 4; ++j) acc[j] = (f32x4){0.f, 0.f, 0.f, 0.f};
      for (int ks = 0; ks < 18; ++ks) {
        int kb = ks * 32 + quad * 8;
        bf16x8 ah, al;
        if (kb < DS) {
          const float* ap = Strue + ((size_t)t * 64 + w * 16 + lrow) * DS + kb;
          float4 x0 = *(const float4*)ap;
          float4 x1 = *(const float4*)(ap + 4);
          float xs[8] = {x0.x, x0.y, x0.z, x0.w, x1.x, x1.y, x1.z, x1.w};
#pragma unroll
          for (int j = 0; j < 8; ++j) {
            unsigned u = __builtin_bit_cast(unsigned, xs[j]);
            unsigned short hh = (unsigned short)(u >> 16);
            ah[j] = (short)hh;
            al[j] = (short)f2bf_rn(xs[j] - bf2f(hh));
          }
        } else {
#pragma unroll
          for (int j = 0; j < 8; ++j) { ah[j] = 0; al[j] = 0; }
        }
#pragma unroll
        for (int j = 0; j < 4; ++j) {
          int n = n0 + j * 16 + lrow;
          bf16x8 bh = *(const bf16x8*)(wc_hi + (size_t)n * DS_PAD + kb);
          bf16x8 bl = *(const bf16x8*)(wc_lo + (size_t)n * DS_PAD + kb);
          acc[j] = mfma16(ah, bh, acc[j]);
          acc[j] = mfma16(al, bh, acc[j]);
          acc[j] = mfma16(ah, bl, acc[j]);
        }
      }
#pragma unroll
      for (int j = 0; j < 4; ++j) {
        int n = n0 + j * 16 + lrow;
#pragma unroll
        for (int r = 0; r < 4; ++r)
          gx[((size_t)t * 64 + w * 16 + quad * 4 + r) * NG + n] =
              (_Float16)acc[j][r];
      }
      __syncthreads();
      if (tid == 0) {
        __builtin_amdgcn_fence(__ATOMIC_RELEASE, "agent");
        __hip_atomic_fetch_add(&gxdone[t], 1u, __ATOMIC_RELAXED,
                               __HIP_MEMORY_SCOPE_AGENT);
      }
      __syncthreads();
    }
    // ---- phase 2: post-nets per decoder step ----
    for (int d = hid0; d < STEPS_DEC; d += NHELP) {
      unsigned tgt = (unsigned)(LTOK + d + 1);
      {
        const unsigned* fp = &flags[(lane & 15) * 64];
        for (;;) {
          unsigned f =
              __hip_atomic_load(fp, __ATOMIC_RELAXED, __HIP_MEMORY_SCOPE_AGENT);
          if (__all(f >= tgt)) break;
          __builtin_amdgcn_s_sleep(8);
        }
      }
      __builtin_amdgcn_fence(__ATOMIC_ACQUIRE, "agent");
      // A-frags from Hbf[d]
      bf16x8 Af[8];
#pragma unroll
      for (int ks = 0; ks < 8; ++ks)
        Af[ks] = *(const bf16x8*)(Hbf + ((size_t)d * 64 + w * 16 + lrow) * 256 +
                                  ks * 32 + quad * 8);
      // W1 -> hid (LDS), relu, bf16
      {
        f32x4 a1[16];
#pragma unroll
        for (int j = 0; j < 16; ++j) a1[j] = (f32x4){0.f, 0.f, 0.f, 0.f};
        for (int ks = 0; ks < 8; ++ks) {
          int kb = ks * 32 + quad * 8;
#pragma unroll
          for (int j = 0; j < 16; ++j) {
            int n = j * 16 + lrow;
            bf16x8 bh = *(const bf16x8*)(w1_hi + (size_t)n * DH + kb);
            bf16x8 bl = *(const bf16x8*)(w1_lo + (size_t)n * DH + kb);
            a1[j] = mfma16(Af[ks], bh, a1[j]);
            a1[j] = mfma16(Af[ks], bl, a1[j]);
          }
        }
#pragma unroll
        for (int j = 0; j < 16; ++j) {
          int n = j * 16 + lrow;
          float bv = post_b1[n];
#pragma unroll
          for (int r = 0; r < 4; ++r) {
            float v = fmaxf(a1[j][r] + bv, 0.f);
            smem.post.hid[(16 * w + quad * 4 + r) * LDH + n] = f2bf_rn(v);
          }
        }
        // SW1 -> sh (LDS)
#pragma unroll
        for (int j = 0; j < 16; ++j) a1[j] = (f32x4){0.f, 0.f, 0.f, 0.f};
        for (int ks = 0; ks < 8; ++ks) {
          int kb = ks * 32 + quad * 8;
#pragma unroll
          for (int j = 0; j < 16; ++j) {
            int n = j * 16 + lrow;
            bf16x8 bh = *(const bf16x8*)(sw1_hi + (size_t)n * DH + kb);
            bf16x8 bl = *(const bf16x8*)(sw1_lo + (size_t)n * DH + kb);
            a1[j] = mfma16(Af[ks], bh, a1[j]);
            a1[j] = mfma16(Af[ks], bl, a1[j]);
          }
        }
#pragma unroll
        for (int j = 0; j < 16; ++j) {
          int n = j * 16 + lrow;
          float bv = stop_b1[n];
#pragma unroll
          for (int r = 0; r < 4; ++r) {
            float v = fmaxf(a1[j][r] + bv, 0.f);
            smem.post.sh[(16 * w + quad * 4 + r) * LDH + n] = f2bf_rn(v);
          }
        }
      }
      __syncthreads();
      // W2: hid @ W2^T + b2 -> outS (fp32)
      {
        bf16x8 Hf[8];
#pragma unroll
        for (int ks = 0; ks < 8; ++ks)
          Hf[ks] = *(const bf16x8*)&smem.post
                        .hid[(16 * w + lrow) * LDH + ks * 32 + quad * 8];
        f32x4 a2[36];
#pragma unroll
        for (int j = 0; j < 36; ++j) a2[j] = (f32x4){0.f, 0.f, 0.f, 0.f};
        for (int ks = 0; ks < 8; ++ks) {
          int kb = ks * 32 + quad * 8;
#pragma unroll
          for (int j = 0; j < 36; ++j) {
            int n = j * 16 + lrow;
            bf16x8 bh = *(const bf16x8*)(w2_hi + (size_t)n * DH + kb);
            bf16x8 bl = *(const bf16x8*)(w2_lo + (size_t)n * DH + kb);
            a2[j] = mfma16(Hf[ks], bh, a2[j]);
            a2[j] = mfma16(Hf[ks], bl, a2[j]);
          }
        }
#pragma unroll
        for (int j = 0; j < 36; ++j) {
          int n = j * 16 + lrow;
          if (n < DS) {
            float bv = post_b2[n];
#pragma unroll
            for (int r = 0; r < 4; ++r)
              outS[((size_t)d * 64 + 16 * w + quad * 4 + r) * DS + n] =
                  a2[j][r] + bv;
          }
        }
      }
      // stop logits from sh
      {
        int bb = tid >> 2, kq = tid & 3;
        float a = 0.f;
        for (int kk = 0; kk < 64; kk += 8) {
          bf16x8 v = *(const bf16x8*)&smem.post.sh[bb * LDH + kq * 64 + kk];
          const float* wp = stop_w2 + kq * 64 + kk;
#pragma unroll
          for (int j = 0; j < 8; ++j) a += bf2f((unsigned short)v[j]) * wp[j];
        }
        smem.post.red[tid] = a;
      }
      __syncthreads();
      if (tid < 64)
        outStop[(size_t)d * 64 + tid] =
            smem.post.red[tid * 4] + smem.post.red[tid * 4 + 1] +
            smem.post.red[tid * 4 + 2] + smem.post.red[tid * 4 + 3] +
            stop_b2[0];
      __syncthreads();
    }
  }
}

extern "C" void kernel_launch(void* const* d_in, const int* in_sizes, int n_in,
                              void* d_out, int out_size, void* d_ws,
                              size_t ws_size, hipStream_t stream) {
  const int* token_pad = (const int*)d_in[0];
  const int* token_len = (const int*)d_in[1];
  const float* S_true = (const float*)d_in[2];
  const float* emb = (const float*)d_in[3];
  const float* enc_Wih = (const float*)d_in[4];
  const float* enc_Whh = (const float*)d_in[5];
  const float* enc_bih = (const float*)d_in[6];
  const float* enc_bhh = (const float*)d_in[7];
  const float* dec_Wih = (const float*)d_in[8];
  const float* dec_Whh = (const float*)d_in[9];
  const float* dec_bih = (const float*)d_in[10];
  const float* dec_bhh = (const float*)d_in[11];
  const float* pre_W = (const float*)d_in[12];
  const float* pre_b = (const float*)d_in[13];
  const float* post_W1 = (const float*)d_in[14];
  const float* post_b1 = (const float*)d_in[15];
  const float* post_W2 = (const float*)d_in[16];
  const float* post_b2 = (const float*)d_in[17];
  const float* stop_W1 = (const float*)d_in[18];
  const float* stop_b1 = (const float*)d_in[19];
  const float* stop_W2 = (const float*)d_in[20];
  const float* stop_b2 = (const float*)d_in[21];

  if (ws_size < WS_NEED) return;
  char* ws = (char*)d_ws;
  unsigned* flags = (unsigned*)(ws + OFF_FLAGS);
  unsigned* gxdone = (unsigned*)(ws + OFF_GXD);
  unsigned short* hpl = (unsigned short*)(ws + OFF_HPL);
  unsigned short* whe_hi = (unsigned short*)(ws + OFF_WHE_HI);
  unsigned short* whe_lo = (unsigned short*)(ws + OFF_WHE_LO);
  unsigned short* whd_hi = (unsigned short*)(ws + OFF_WHD_HI);
  unsigned short* whd_lo = (unsigned short*)(ws + OFF_WHD_LO);
  unsigned short* wc_hi = (unsigned short*)(ws + OFF_WC_HI);
  unsigned short* wc_lo = (unsigned short*)(ws + OFF_WC_LO);
  unsigned short* w1_hi = (unsigned short*)(ws + OFF_W1_HI);
  unsigned short* w1_lo = (unsigned short*)(ws + OFF_W1_LO);
  unsigned short* w2_hi = (unsigned short*)(ws + OFF_W2_HI);
  unsigned short* w2_lo = (unsigned short*)(ws + OFF_W2_LO);
  unsigned short* sw1_hi = (unsigned short*)(ws + OFF_SW1_HI);
  unsigned short* sw1_lo = (unsigned short*)(ws + OFF_SW1_LO);
  float* emb2 = (float*)(ws + OFF_EMB2);
  float* bcomb = (float*)(ws + OFF_BCOMB);
  float* WcombF = (float*)(ws + OFF_WCF);
  unsigned short* Hbf = (unsigned short*)(ws + OFF_HBF);
  _Float16* gx = (_Float16*)(ws + OFF_GX);
  float* outS = (float*)d_out;
  float* outStop = outS + (size_t)STEPS_DEC * 64 * DS;

  hipMemsetAsync(ws + OFF_FLAGS, 0, 139264, stream);      // flags+gxdone+hpl
  hipMemsetAsync(ws + OFF_WC_HI, 0, 2359296, stream);     // wc pad cols
  hipMemsetAsync(ws + OFF_W2_HI, 0, 589824, stream);      // w2 pad rows

  prep_wcomb_kernel<<<1024, 256, 0, stream>>>(dec_Wih, pre_W, pre_b, dec_bih,
                                              dec_bhh, WcombF, bcomb);
  prep_emb2_kernel<<<148, 256, 0, stream>>>(emb, enc_Wih, enc_bih, enc_bhh,
                                            emb2);
  split_bf16_kernel<<<(1024 * 552 + 255) / 256, 256, 0, stream>>>(
      WcombF, wc_hi, wc_lo, 1024, 552, 576);
  split_bf16_kernel<<<(1024 * 256 + 255) / 256, 256, 0, stream>>>(
      dec_Whh, whd_hi, whd_lo, 1024, 256, 256);
  split_bf16_kernel<<<(1024 * 256 + 255) / 256, 256, 0, stream>>>(
      enc_Whh, whe_hi, whe_lo, 1024, 256, 256);
  split_bf16_kernel<<<(256 * 256 + 255) / 256, 256, 0, stream>>>(
      post_W1, w1_hi, w1_lo, 256, 256, 256);
  split_bf16_kernel<<<(552 * 256 + 255) / 256, 256, 0, stream>>>(
      post_W2, w2_hi, w2_lo, 552, 256, 256);
  split_bf16_kernel<<<(256 * 256 + 255) / 256, 256, 0, stream>>>(
      stop_W1, sw1_hi, sw1_lo, 256, 256, 256);

  mega_kernel<<<GRID_BLKS, 256, 0, stream>>>(
      whe_hi, whe_lo, whd_hi, whd_lo, wc_hi, wc_lo, w1_hi, w1_lo, w2_hi, w2_lo,
      sw1_hi, sw1_lo, emb2, bcomb, token_pad, token_len, S_true, post_b1,
      post_b2, stop_b1, stop_W2, stop_b2, hpl, Hbf, gx, flags, gxdone, outS,
      outStop);
}